// Round 19
// baseline (48.629 us; speedup 1.0000x reference)
//
#include <hip/hip_runtime.h>

#define B_   4
#define C_   64
#define H_   128
#define W_   128
#define KS   7
#define G_   4
#define GC_  16
#define KK   49
#define PAD  3
#define TH   8
#define TW   16
#define HW_  (H_ * W_)
#define ZKHB 2112              // bytes per kh plane: 128px*16B + 64B bank shift

typedef float f32x4  __attribute__((ext_vector_type(4)));
typedef short bf16x8 __attribute__((ext_vector_type(8)));
typedef unsigned int u32x4 __attribute__((ext_vector_type(4)));
typedef unsigned int u32x2 __attribute__((ext_vector_type(2)));
typedef __fp16 h16x2 __attribute__((ext_vector_type(2)));

__device__ __forceinline__ unsigned f2bf(float f) {
    unsigned u = __float_as_uint(f);
    unsigned r = u + 0x7FFFu + ((u >> 16) & 1u);
    return r >> 16;
}
__device__ __forceinline__ unsigned pk2(float a, float b) {
    union { h16x2 h; unsigned u; } x;
    x.h = __builtin_amdgcn_cvt_pkrtz(a, b);
    return x.u;
}
__device__ __forceinline__ h16x2 ash2(unsigned u) {
    union { unsigned u; h16x2 h; } x; x.u = u; return x.h;
}
__device__ __forceinline__ unsigned short f16b(float f) {
    union { __fp16 h; unsigned short s; } x; x.h = (__fp16)f; return x.s;
}
#if __has_builtin(__builtin_amdgcn_fdot2)
#define DOT2(a, b, c) __builtin_amdgcn_fdot2((a), (b), (c), false)
#else
#define DOT2(a, b, c) ((c) + (float)(a)[0] * (float)(b)[0] + (float)(a)[1] * (float)(b)[1])
#endif
#define AB(a, b) __builtin_amdgcn_alignbit((a), (b), 16)

// ======== prep: xT[b][hw][c] bf16, BN-folded bf16 weights, folded bias ======
__global__ __launch_bounds__(256) void prep(
    const float* __restrict__ x,
    const float* __restrict__ cw,
    const float* __restrict__ bng,
    const float* __restrict__ bnb,
    const float* __restrict__ bnm,
    const float* __restrict__ bnv,
    unsigned short* __restrict__ xT,
    unsigned short* __restrict__ cwb,
    float* __restrict__ sb)
{
    const int tid = threadIdx.x;
    const int bid = blockIdx.x;
    if (bid < 1024) {
        __shared__ unsigned short t[64][68];
        const int b   = bid >> 8;
        const int px0 = (bid & 255) * 64;
        const float* xb = x + (size_t)b * C_ * HW_ + px0;
#pragma unroll
        for (int it = 0; it < 16; ++it) {
            const int i = it * 256 + tid;
            const int c = i >> 6, p = i & 63;
            t[p][c] = (unsigned short)f2bf(xb[(size_t)c * HW_ + p]);
        }
        __syncthreads();
        const int p = tid >> 2, q = tid & 3;
        unsigned int o[8];
#pragma unroll
        for (int j = 0; j < 8; ++j)
            o[j] = (unsigned)t[p][q * 16 + 2 * j] | ((unsigned)t[p][q * 16 + 2 * j + 1] << 16);
        unsigned int* dst = (unsigned int*)(xT + ((size_t)(b * HW_ + px0 + p)) * C_ + q * 16);
        u32x4 v0, v1;
        v0[0] = o[0]; v0[1] = o[1]; v0[2] = o[2]; v0[3] = o[3];
        v1[0] = o[4]; v1[1] = o[5]; v1[2] = o[6]; v1[3] = o[7];
        *(u32x4*)dst = v0;
        *(u32x4*)(dst + 4) = v1;
    } else {
        if (tid < 196) {
            const float sc = bng[tid] * rsqrtf(bnv[tid] + 1e-5f);
            sb[tid] = bnb[tid] - bnm[tid] * sc;
        }
        const int g  = tid >> 6;
        const int kp = tid & 63;
        unsigned int* dst = (unsigned int*)(cwb + ((size_t)(g * 64 + kp)) * C_);
        if (kp < KK) {
            const int o = g * KK + kp;
            const float sc = bng[o] * rsqrtf(bnv[o] + 1e-5f);
            const float* wp = cw + (size_t)o * C_;
#pragma unroll
            for (int c = 0; c < C_; c += 2)
                dst[c >> 1] = f2bf(wp[c] * sc) | (f2bf(wp[c + 1] * sc) << 16);
        } else {
#pragma unroll
            for (int c2 = 0; c2 < C_ / 2; ++c2) dst[c2] = 0u;
        }
    }
}

// ---- involution phase macros: pure named-SSA (r16 lesson) ----
#define LOADQ(S, KH_) do {                                                     \
    const int gh_  = h0 + y8 + (KH_) - PAD;                                    \
    const int ghc_ = gh_ < 0 ? 0 : (gh_ > H_ - 1 ? H_ - 1 : gh_);              \
    const float* rp_ = xc + (size_t)ghc_ * W_;                                 \
    if (ledge) {                                                               \
        const f32x4* vp_ = (const f32x4*)rp_;                                  \
        q##S##0 = vp_[0]; q##S##1 = vp_[1]; q##S##2 = vp_[2];                  \
    } else if (redge) {                                                        \
        const f32x4* vp_ = (const f32x4*)(rp_ + 116);                          \
        q##S##0 = vp_[0]; q##S##1 = vp_[1]; q##S##2 = vp_[2];                  \
    } else {                                                                   \
        const f32x4* vp_ = (const f32x4*)(rp_ + w0 + xh * 8 - 4);              \
        q##S##0 = vp_[0]; q##S##1 = vp_[1]; q##S##2 = vp_[2]; q##S##3 = vp_[3];\
    }                                                                          \
} while (0)

#define PACKD(S) do {                                                          \
    if (ledge) {                                                               \
        d##S##0 = 0u;                                                          \
        d##S##1 = pk2(0.f, q##S##0[0]);                                        \
        d##S##2 = pk2(q##S##0[1], q##S##0[2]);                                 \
        d##S##3 = pk2(q##S##0[3], q##S##1[0]);                                 \
        d##S##4 = pk2(q##S##1[1], q##S##1[2]);                                 \
        d##S##5 = pk2(q##S##1[3], q##S##2[0]);                                 \
        d##S##6 = pk2(q##S##2[1], q##S##2[2]);                                 \
    } else if (redge) {                                                        \
        d##S##0 = pk2(q##S##0[1], q##S##0[2]);                                 \
        d##S##1 = pk2(q##S##0[3], q##S##1[0]);                                 \
        d##S##2 = pk2(q##S##1[1], q##S##1[2]);                                 \
        d##S##3 = pk2(q##S##1[3], q##S##2[0]);                                 \
        d##S##4 = pk2(q##S##2[1], q##S##2[2]);                                 \
        d##S##5 = pk2(q##S##2[3], 0.f);                                        \
        d##S##6 = 0u;                                                          \
    } else {                                                                   \
        d##S##0 = pk2(q##S##0[1], q##S##0[2]);                                 \
        d##S##1 = pk2(q##S##0[3], q##S##1[0]);                                 \
        d##S##2 = pk2(q##S##1[1], q##S##1[2]);                                 \
        d##S##3 = pk2(q##S##1[3], q##S##2[0]);                                 \
        d##S##4 = pk2(q##S##2[1], q##S##2[2]);                                 \
        d##S##5 = pk2(q##S##2[3], q##S##3[0]);                                 \
        d##S##6 = pk2(q##S##3[1], q##S##3[2]);                                 \
    }                                                                          \
} while (0)

#define FMAD(S, KH_) do {                                                      \
    const int gh_ = h0 + y8 + (KH_) - PAD;                                     \
    if (gh_ >= 0 && gh_ < H_) {                                                \
        const int zo_ = (KH_) * ZKHB;                                          \
        const unsigned r0_ = AB(d##S##1, d##S##0);                             \
        const unsigned r1_ = AB(d##S##2, d##S##1);                             \
        const unsigned r2_ = AB(d##S##3, d##S##2);                             \
        const unsigned r3_ = AB(d##S##4, d##S##3);                             \
        const unsigned r4_ = AB(d##S##5, d##S##4);                             \
        const unsigned r5_ = AB(d##S##6, d##S##5);                             \
        const unsigned r6_ = AB(d##S##6, d##S##6);                             \
        u32x4 q_;                                                              \
        q_ = *(const u32x4*)(zp0 + zo_);                                       \
        a0 = DOT2(ash2(q_[0]), ash2(d##S##0), a0);                             \
        a0 = DOT2(ash2(q_[1]), ash2(d##S##1), a0);                             \
        a0 = DOT2(ash2(q_[2]), ash2(d##S##2), a0);                             \
        a0 = DOT2(ash2(q_[3]), ash2(d##S##3), a0);                             \
        q_ = *(const u32x4*)(zp1 + zo_);                                       \
        a1 = DOT2(ash2(q_[0]), ash2(r0_), a1);                                 \
        a1 = DOT2(ash2(q_[1]), ash2(r1_), a1);                                 \
        a1 = DOT2(ash2(q_[2]), ash2(r2_), a1);                                 \
        a1 = DOT2(ash2(q_[3]), ash2(r3_), a1);                                 \
        q_ = *(const u32x4*)(zp2 + zo_);                                       \
        a2 = DOT2(ash2(q_[0]), ash2(d##S##1), a2);                             \
        a2 = DOT2(ash2(q_[1]), ash2(d##S##2), a2);                             \
        a2 = DOT2(ash2(q_[2]), ash2(d##S##3), a2);                             \
        a2 = DOT2(ash2(q_[3]), ash2(d##S##4), a2);                             \
        q_ = *(const u32x4*)(zp3 + zo_);                                       \
        a3 = DOT2(ash2(q_[0]), ash2(r1_), a3);                                 \
        a3 = DOT2(ash2(q_[1]), ash2(r2_), a3);                                 \
        a3 = DOT2(ash2(q_[2]), ash2(r3_), a3);                                 \
        a3 = DOT2(ash2(q_[3]), ash2(r4_), a3);                                 \
        q_ = *(const u32x4*)(zp4 + zo_);                                       \
        a4 = DOT2(ash2(q_[0]), ash2(d##S##2), a4);                             \
        a4 = DOT2(ash2(q_[1]), ash2(d##S##3), a4);                             \
        a4 = DOT2(ash2(q_[2]), ash2(d##S##4), a4);                             \
        a4 = DOT2(ash2(q_[3]), ash2(d##S##5), a4);                             \
        q_ = *(const u32x4*)(zp5 + zo_);                                       \
        a5 = DOT2(ash2(q_[0]), ash2(r2_), a5);                                 \
        a5 = DOT2(ash2(q_[1]), ash2(r3_), a5);                                 \
        a5 = DOT2(ash2(q_[2]), ash2(r4_), a5);                                 \
        a5 = DOT2(ash2(q_[3]), ash2(r5_), a5);                                 \
        q_ = *(const u32x4*)(zp6 + zo_);                                       \
        a6 = DOT2(ash2(q_[0]), ash2(d##S##3), a6);                             \
        a6 = DOT2(ash2(q_[1]), ash2(d##S##4), a6);                             \
        a6 = DOT2(ash2(q_[2]), ash2(d##S##5), a6);                             \
        a6 = DOT2(ash2(q_[3]), ash2(d##S##6), a6);                             \
        q_ = *(const u32x4*)(zp7 + zo_);                                       \
        a7 = DOT2(ash2(q_[0]), ash2(r3_), a7);                                 \
        a7 = DOT2(ash2(q_[1]), ash2(r4_), a7);                                 \
        a7 = DOT2(ash2(q_[2]), ash2(r5_), a7);                                 \
        a7 = DOT2(ash2(q_[3]), ash2(r6_), a7);                                 \
    }                                                                          \
} while (0)

// ======== main: wave-synchronous conv+involution, 5 blocks/CU ========
// vs r18: (a) launch_bounds (256,5) for +25% TLP (latency-stall diagnosis);
// (b) conv restructured per-nt (B-frag + MFMA + epilogue fused) cutting peak
// live regs by ~48 so the 102-VGPR cap cannot spill; (c) first involution
// row-load hoisted above the conv to hide its latency under the conv phase.
__global__ __launch_bounds__(256, 5) void invol_mfma14(
    const float* __restrict__ x,
    const unsigned short* __restrict__ xT,
    const unsigned short* __restrict__ cwb,
    const float* __restrict__ sb,
    float* __restrict__ out)
{
    // z layout: addr = kh*2112 + (px*16 ^ ((px>>3&7)<<4)) + kw*2  (f16)
    __shared__ __align__(16) char z_sh[KS * ZKHB];   // 14784 B

    const int tid  = threadIdx.x;
    const int lane = tid & 63;
    const int wv   = tid >> 6;
    const int l15  = lane & 15;
    const int l4   = lane >> 4;

    // XCD-locality swizzle (r13: FETCH 37->27 MB)
    const int bid = blockIdx.x;
    const int xcd = bid & 7;
    const int s   = bid >> 3;
    const int b   = xcd >> 1;
    const int g   = (xcd & 1) * 2 + (s >> 7);
    const int by  = (s >> 3) & 15;
    const int bx  = s & 7;
    const int w0  = bx * TW;
    const int h0  = by * TH;

    // consumer map (barrier-free: wave consumes its own z rows)
    const int y8 = tid >> 5;           // wave = y8>>1 (= wv)
    const int c2 = (tid >> 1) & 15;
    const int xh = tid & 1;
    const bool ledge = (bx == 0) & (xh == 0);
    const bool redge = (bx == W_ / TW - 1) & (xh == 1);
    const float* xc = x + (size_t)(b * C_ + g * GC_ + c2) * HW_;

    f32x4 qA0 = {0,0,0,0}, qA1 = {0,0,0,0}, qA2 = {0,0,0,0}, qA3 = {0,0,0,0};
    f32x4 qB0 = {0,0,0,0}, qB1 = {0,0,0,0}, qB2 = {0,0,0,0}, qB3 = {0,0,0,0};
    unsigned dA0, dA1, dA2, dA3, dA4, dA5, dA6;
    unsigned dB0, dB1, dB2, dB3, dB4, dB5, dB6;

    LOADQ(A, 0);   // issue first involution row NOW: latency hides under conv

    // folded bias, direct per-lane global loads
    float bi0, bi1, bi2, bi3;
    {
        const float* sg = sb + g * KK;
        bi0 = sg[l15];
        bi1 = sg[16 + l15];
        bi2 = sg[32 + l15];
        bi3 = (48 + l15 < KK) ? sg[48 + l15] : 0.f;
    }

    // A fragments (xT: [hw][c] bf16)
    bf16x8 afr[2][2];
    {
        const unsigned short* xTb = xT + (size_t)b * HW_ * C_;
#pragma unroll
        for (int mt = 0; mt < 2; ++mt) {
            const int hh = h0 + wv * 2 + mt;
            const unsigned short* xp = xTb + ((size_t)(hh * W_ + w0 + l15)) * C_;
#pragma unroll
            for (int ks = 0; ks < 2; ++ks)
                afr[mt][ks] = *(const bf16x8*)(xp + ks * 32 + l4 * 8);
        }
    }

    // conv per-nt: B-frag load + MFMA + epilogue fused (low peak VGPR)
    {
        const unsigned short* cwg = cwb + (size_t)g * 64 * C_;
#pragma unroll
        for (int nt = 0; nt < 4; ++nt) {
            const int k = nt * 16 + l15;
            const bf16x8 bf0 = *(const bf16x8*)(cwg + k * C_ + l4 * 8);
            const bf16x8 bf1 = *(const bf16x8*)(cwg + k * C_ + 32 + l4 * 8);
            const float bi = (nt == 0) ? bi0 : (nt == 1) ? bi1 : (nt == 2) ? bi2 : bi3;
            const int kh = (k * 9363) >> 16;        // k/7
            const int kw = k - kh * 7;
            const int kbase = kh * ZKHB + kw * 2;
            const int khp = k - KK;
#pragma unroll
            for (int mt = 0; mt < 2; ++mt) {
                f32x4 a = {0.f, 0.f, 0.f, 0.f};
                a = __builtin_amdgcn_mfma_f32_16x16x32_bf16(afr[mt][0], bf0, a, 0, 0, 0);
                a = __builtin_amdgcn_mfma_f32_16x16x32_bf16(afr[mt][1], bf1, a, 0, 0, 0);
                const int px0 = (wv * 2 + mt) * 16 + l4 * 4;
                if (k < KK) {
#pragma unroll
                    for (int r = 0; r < 4; ++r) {
                        const int px = px0 + r;
                        const int sw = (px << 4) ^ (((px >> 3) & 7) << 4);
                        const float t = a[r] + bi;
                        const float v = __fdividef(t, 1.0f + __expf(-t));
                        *(unsigned short*)(z_sh + kbase + sw) = f16b(v);
                    }
                } else if (k < 56) {                // zero the 8th-tap pad
#pragma unroll
                    for (int r = 0; r < 4; ++r) {
                        const int px = px0 + r;
                        const int sw = (px << 4) ^ (((px >> 3) & 7) << 4);
                        *(unsigned short*)(z_sh + khp * ZKHB + sw + 14) = 0;
                    }
                }
            }
        }
    }

    // involution (no barrier: z rows produced by this same wave)
    float a0 = 0.f, a1 = 0.f, a2 = 0.f, a3 = 0.f;
    float a4 = 0.f, a5 = 0.f, a6 = 0.f, a7 = 0.f;

    const int pxb = y8 * 16 + xh * 8;
    const int mx  = ((2 * y8 + xh) & 7) << 4;
    const char* zbase = z_sh + (pxb << 4);
    const char* zp0 = zbase + ((0 << 4) ^ mx);
    const char* zp1 = zbase + ((1 << 4) ^ mx);
    const char* zp2 = zbase + ((2 << 4) ^ mx);
    const char* zp3 = zbase + ((3 << 4) ^ mx);
    const char* zp4 = zbase + ((4 << 4) ^ mx);
    const char* zp5 = zbase + ((5 << 4) ^ mx);
    const char* zp6 = zbase + ((6 << 4) ^ mx);
    const char* zp7 = zbase + ((7 << 4) ^ mx);

#pragma unroll 1
    for (int kh2 = 0; kh2 < 3; ++kh2) {             // kh rolled (r4 spill lesson)
        LOADQ(B, 2 * kh2 + 1);
        PACKD(A); FMAD(A, 2 * kh2);
        LOADQ(A, 2 * kh2 + 2);
        PACKD(B); FMAD(B, 2 * kh2 + 1);
    }
    PACKD(A); FMAD(A, 6);

    float* og = out + (size_t)(b * C_ + g * GC_ + c2) * HW_
                    + (h0 + y8) * W_ + w0 + xh * 8;
    {
        f32x4 v;
        v[0] = a0; v[1] = a1; v[2] = a2; v[3] = a3;
        *(f32x4*)(og + 0) = v;
        v[0] = a4; v[1] = a5; v[2] = a6; v[3] = a7;
        *(f32x4*)(og + 4) = v;
    }
}

extern "C" void kernel_launch(void* const* d_in, const int* in_sizes, int n_in,
                              void* d_out, int out_size, void* d_ws, size_t ws_size,
                              hipStream_t stream) {
    const float* x   = (const float*)d_in[0];
    const float* cw  = (const float*)d_in[1];
    const float* bng = (const float*)d_in[2];
    const float* bnb = (const float*)d_in[3];
    const float* bnm = (const float*)d_in[4];
    const float* bnv = (const float*)d_in[5];
    float* out = (float*)d_out;

    unsigned short* xT  = (unsigned short*)d_ws;                 // 8,388,608 B
    unsigned short* cwb = xT + (size_t)B_ * HW_ * C_;            // 32,768 B
    float*          sbp = (float*)(cwb + (size_t)G_ * 64 * C_);  // 784 B

    prep<<<dim3(1025), dim3(256), 0, stream>>>(x, cw, bng, bnb, bnm, bnv,
                                               xT, cwb, sbp);
    invol_mfma14<<<dim3(2048), dim3(256), 0, stream>>>(x, xT, cwb, sbp, out);
}

// Round 20
// 46.802 us; speedup vs baseline: 1.0390x; 1.0390x over previous
//
#include <hip/hip_runtime.h>

#define B_   4
#define C_   64
#define H_   128
#define W_   128
#define KS   7
#define G_   4
#define GC_  16
#define KK   49
#define PAD  3
#define TH   8
#define TW   16
#define HW_  (H_ * W_)
#define ZKHB 2112              // bytes per kh plane: 128px*16B + 64B bank shift

typedef float f32x4  __attribute__((ext_vector_type(4)));
typedef short bf16x8 __attribute__((ext_vector_type(8)));
typedef unsigned int u32x4 __attribute__((ext_vector_type(4)));
typedef unsigned int u32x2 __attribute__((ext_vector_type(2)));
typedef __fp16 h16x2 __attribute__((ext_vector_type(2)));

__device__ __forceinline__ unsigned f2bf(float f) {
    unsigned u = __float_as_uint(f);
    unsigned r = u + 0x7FFFu + ((u >> 16) & 1u);
    return r >> 16;
}
__device__ __forceinline__ unsigned pk2(float a, float b) {
    union { h16x2 h; unsigned u; } x;
    x.h = __builtin_amdgcn_cvt_pkrtz(a, b);
    return x.u;
}
__device__ __forceinline__ h16x2 ash2(unsigned u) {
    union { unsigned u; h16x2 h; } x; x.u = u; return x.h;
}
__device__ __forceinline__ unsigned short f16b(float f) {
    union { __fp16 h; unsigned short s; } x; x.h = (__fp16)f; return x.s;
}
#if __has_builtin(__builtin_amdgcn_fdot2)
#define DOT2(a, b, c) __builtin_amdgcn_fdot2((a), (b), (c), false)
#else
#define DOT2(a, b, c) ((c) + (float)(a)[0] * (float)(b)[0] + (float)(a)[1] * (float)(b)[1])
#endif
#define AB(a, b) __builtin_amdgcn_alignbit((a), (b), 16)

// ======== prep: xT[b][hw][c] bf16, BN-folded bf16 weights, folded bias ======
__global__ __launch_bounds__(256) void prep(
    const float* __restrict__ x,
    const float* __restrict__ cw,
    const float* __restrict__ bng,
    const float* __restrict__ bnb,
    const float* __restrict__ bnm,
    const float* __restrict__ bnv,
    unsigned short* __restrict__ xT,
    unsigned short* __restrict__ cwb,
    float* __restrict__ sb)
{
    const int tid = threadIdx.x;
    const int bid = blockIdx.x;
    if (bid < 1024) {
        __shared__ unsigned short t[64][68];
        const int b   = bid >> 8;
        const int px0 = (bid & 255) * 64;
        const float* xb = x + (size_t)b * C_ * HW_ + px0;
#pragma unroll
        for (int it = 0; it < 16; ++it) {
            const int i = it * 256 + tid;
            const int c = i >> 6, p = i & 63;
            t[p][c] = (unsigned short)f2bf(xb[(size_t)c * HW_ + p]);
        }
        __syncthreads();
        const int p = tid >> 2, q = tid & 3;
        unsigned int o[8];
#pragma unroll
        for (int j = 0; j < 8; ++j)
            o[j] = (unsigned)t[p][q * 16 + 2 * j] | ((unsigned)t[p][q * 16 + 2 * j + 1] << 16);
        unsigned int* dst = (unsigned int*)(xT + ((size_t)(b * HW_ + px0 + p)) * C_ + q * 16);
        u32x4 v0, v1;
        v0[0] = o[0]; v0[1] = o[1]; v0[2] = o[2]; v0[3] = o[3];
        v1[0] = o[4]; v1[1] = o[5]; v1[2] = o[6]; v1[3] = o[7];
        *(u32x4*)dst = v0;
        *(u32x4*)(dst + 4) = v1;
    } else {
        if (tid < 196) {
            const float sc = bng[tid] * rsqrtf(bnv[tid] + 1e-5f);
            sb[tid] = bnb[tid] - bnm[tid] * sc;
        }
        const int g  = tid >> 6;
        const int kp = tid & 63;
        unsigned int* dst = (unsigned int*)(cwb + ((size_t)(g * 64 + kp)) * C_);
        if (kp < KK) {
            const int o = g * KK + kp;
            const float sc = bng[o] * rsqrtf(bnv[o] + 1e-5f);
            const float* wp = cw + (size_t)o * C_;
#pragma unroll
            for (int c = 0; c < C_; c += 2)
                dst[c >> 1] = f2bf(wp[c] * sc) | (f2bf(wp[c + 1] * sc) << 16);
        } else {
#pragma unroll
            for (int c2 = 0; c2 < C_ / 2; ++c2) dst[c2] = 0u;
        }
    }
}

// ---- involution phase macros: pure named-SSA (r16 lesson) ----
#define LOADQ(S, KH_) do {                                                     \
    const int gh_  = h0 + y8 + (KH_) - PAD;                                    \
    const int ghc_ = gh_ < 0 ? 0 : (gh_ > H_ - 1 ? H_ - 1 : gh_);              \
    const float* rp_ = xc + (size_t)ghc_ * W_;                                 \
    if (ledge) {                                                               \
        const f32x4* vp_ = (const f32x4*)rp_;                                  \
        q##S##0 = vp_[0]; q##S##1 = vp_[1]; q##S##2 = vp_[2];                  \
    } else if (redge) {                                                        \
        const f32x4* vp_ = (const f32x4*)(rp_ + 116);                          \
        q##S##0 = vp_[0]; q##S##1 = vp_[1]; q##S##2 = vp_[2];                  \
    } else {                                                                   \
        const f32x4* vp_ = (const f32x4*)(rp_ + w0 + xh * 8 - 4);              \
        q##S##0 = vp_[0]; q##S##1 = vp_[1]; q##S##2 = vp_[2]; q##S##3 = vp_[3];\
    }                                                                          \
} while (0)

#define PACKD(S) do {                                                          \
    if (ledge) {                                                               \
        d##S##0 = 0u;                                                          \
        d##S##1 = pk2(0.f, q##S##0[0]);                                        \
        d##S##2 = pk2(q##S##0[1], q##S##0[2]);                                 \
        d##S##3 = pk2(q##S##0[3], q##S##1[0]);                                 \
        d##S##4 = pk2(q##S##1[1], q##S##1[2]);                                 \
        d##S##5 = pk2(q##S##1[3], q##S##2[0]);                                 \
        d##S##6 = pk2(q##S##2[1], q##S##2[2]);                                 \
    } else if (redge) {                                                        \
        d##S##0 = pk2(q##S##0[1], q##S##0[2]);                                 \
        d##S##1 = pk2(q##S##0[3], q##S##1[0]);                                 \
        d##S##2 = pk2(q##S##1[1], q##S##1[2]);                                 \
        d##S##3 = pk2(q##S##1[3], q##S##2[0]);                                 \
        d##S##4 = pk2(q##S##2[1], q##S##2[2]);                                 \
        d##S##5 = pk2(q##S##2[3], 0.f);                                        \
        d##S##6 = 0u;                                                          \
    } else {                                                                   \
        d##S##0 = pk2(q##S##0[1], q##S##0[2]);                                 \
        d##S##1 = pk2(q##S##0[3], q##S##1[0]);                                 \
        d##S##2 = pk2(q##S##1[1], q##S##1[2]);                                 \
        d##S##3 = pk2(q##S##1[3], q##S##2[0]);                                 \
        d##S##4 = pk2(q##S##2[1], q##S##2[2]);                                 \
        d##S##5 = pk2(q##S##2[3], q##S##3[0]);                                 \
        d##S##6 = pk2(q##S##3[1], q##S##3[2]);                                 \
    }                                                                          \
} while (0)

#define FMAD(S, KH_) do {                                                      \
    const int gh_ = h0 + y8 + (KH_) - PAD;                                     \
    if (gh_ >= 0 && gh_ < H_) {                                                \
        const int zo_ = (KH_) * ZKHB;                                          \
        const unsigned r0_ = AB(d##S##1, d##S##0);                             \
        const unsigned r1_ = AB(d##S##2, d##S##1);                             \
        const unsigned r2_ = AB(d##S##3, d##S##2);                             \
        const unsigned r3_ = AB(d##S##4, d##S##3);                             \
        const unsigned r4_ = AB(d##S##5, d##S##4);                             \
        const unsigned r5_ = AB(d##S##6, d##S##5);                             \
        const unsigned r6_ = AB(d##S##6, d##S##6);                             \
        u32x4 q_;                                                              \
        q_ = *(const u32x4*)(zp0 + zo_);                                       \
        a0 = DOT2(ash2(q_[0]), ash2(d##S##0), a0);                             \
        a0 = DOT2(ash2(q_[1]), ash2(d##S##1), a0);                             \
        a0 = DOT2(ash2(q_[2]), ash2(d##S##2), a0);                             \
        a0 = DOT2(ash2(q_[3]), ash2(d##S##3), a0);                             \
        q_ = *(const u32x4*)(zp1 + zo_);                                       \
        a1 = DOT2(ash2(q_[0]), ash2(r0_), a1);                                 \
        a1 = DOT2(ash2(q_[1]), ash2(r1_), a1);                                 \
        a1 = DOT2(ash2(q_[2]), ash2(r2_), a1);                                 \
        a1 = DOT2(ash2(q_[3]), ash2(r3_), a1);                                 \
        q_ = *(const u32x4*)(zp2 + zo_);                                       \
        a2 = DOT2(ash2(q_[0]), ash2(d##S##1), a2);                             \
        a2 = DOT2(ash2(q_[1]), ash2(d##S##2), a2);                             \
        a2 = DOT2(ash2(q_[2]), ash2(d##S##3), a2);                             \
        a2 = DOT2(ash2(q_[3]), ash2(d##S##4), a2);                             \
        q_ = *(const u32x4*)(zp3 + zo_);                                       \
        a3 = DOT2(ash2(q_[0]), ash2(r1_), a3);                                 \
        a3 = DOT2(ash2(q_[1]), ash2(r2_), a3);                                 \
        a3 = DOT2(ash2(q_[2]), ash2(r3_), a3);                                 \
        a3 = DOT2(ash2(q_[3]), ash2(r4_), a3);                                 \
        q_ = *(const u32x4*)(zp4 + zo_);                                       \
        a4 = DOT2(ash2(q_[0]), ash2(d##S##2), a4);                             \
        a4 = DOT2(ash2(q_[1]), ash2(d##S##3), a4);                             \
        a4 = DOT2(ash2(q_[2]), ash2(d##S##4), a4);                             \
        a4 = DOT2(ash2(q_[3]), ash2(d##S##5), a4);                             \
        q_ = *(const u32x4*)(zp5 + zo_);                                       \
        a5 = DOT2(ash2(q_[0]), ash2(r2_), a5);                                 \
        a5 = DOT2(ash2(q_[1]), ash2(r3_), a5);                                 \
        a5 = DOT2(ash2(q_[2]), ash2(r4_), a5);                                 \
        a5 = DOT2(ash2(q_[3]), ash2(r5_), a5);                                 \
        q_ = *(const u32x4*)(zp6 + zo_);                                       \
        a6 = DOT2(ash2(q_[0]), ash2(d##S##3), a6);                             \
        a6 = DOT2(ash2(q_[1]), ash2(d##S##4), a6);                             \
        a6 = DOT2(ash2(q_[2]), ash2(d##S##5), a6);                             \
        a6 = DOT2(ash2(q_[3]), ash2(d##S##6), a6);                             \
        q_ = *(const u32x4*)(zp7 + zo_);                                       \
        a7 = DOT2(ash2(q_[0]), ash2(r3_), a7);                                 \
        a7 = DOT2(ash2(q_[1]), ash2(r4_), a7);                                 \
        a7 = DOT2(ash2(q_[2]), ash2(r5_), a7);                                 \
        a7 = DOT2(ash2(q_[3]), ash2(r6_), a7);                                 \
    }                                                                          \
} while (0)

// ======== main: r17 structure + early first-row load + 3-deep row pipeline ==
__global__ __launch_bounds__(256, 4) void invol_mfma15(
    const float* __restrict__ x,
    const unsigned short* __restrict__ xT,
    const unsigned short* __restrict__ cwb,
    const float* __restrict__ sb,
    float* __restrict__ out)
{
    // z layout: addr = kh*2112 + (px*16 ^ ((px>>3&7)<<4)) + kw*2  (f16)
    __shared__ __align__(16) char z_sh[KS * ZKHB];   // 14784 B
    __shared__ float sbias[KK];

    const int tid  = threadIdx.x;
    const int lane = tid & 63;
    const int wv   = tid >> 6;
    const int l15  = lane & 15;
    const int l4   = lane >> 4;

    // XCD-locality swizzle (r13: FETCH 37->27 MB)
    const int bid = blockIdx.x;
    const int xcd = bid & 7;
    const int s   = bid >> 3;
    const int b   = xcd >> 1;
    const int g   = (xcd & 1) * 2 + (s >> 7);
    const int by  = (s >> 3) & 15;
    const int bx  = s & 7;
    const int w0  = bx * TW;
    const int h0  = by * TH;

    // involution thread mapping (r17 proven variant)
    const int c2 = tid >> 4;
    const int y8 = (tid >> 1) & 7;
    const int xh = tid & 1;
    const bool ledge = (bx == 0) & (xh == 0);
    const bool redge = (bx == W_ / TW - 1) & (xh == 1);
    const float* xc = x + (size_t)(b * C_ + g * GC_ + c2) * HW_;

    f32x4 qA0 = {0,0,0,0}, qA1 = {0,0,0,0}, qA2 = {0,0,0,0}, qA3 = {0,0,0,0};
    f32x4 qB0 = {0,0,0,0}, qB1 = {0,0,0,0}, qB2 = {0,0,0,0}, qB3 = {0,0,0,0};
    f32x4 qC0 = {0,0,0,0}, qC1 = {0,0,0,0}, qC2 = {0,0,0,0}, qC3 = {0,0,0,0};
    unsigned dA0, dA1, dA2, dA3, dA4, dA5, dA6;
    unsigned dB0, dB1, dB2, dB3, dB4, dB5, dB6;
    unsigned dC0, dC1, dC2, dC3, dC4, dC5, dC6;

    LOADQ(A, 0);   // issue first involution row NOW: latency hides under conv

    if (tid < KK) sbias[tid] = sb[g * KK + tid];

    // ---- A fragments (xT: [hw][c] bf16) ----
    bf16x8 afr[2][2];
    {
        const unsigned short* xTb = xT + (size_t)b * HW_ * C_;
#pragma unroll
        for (int mt = 0; mt < 2; ++mt) {
            const int hh = h0 + wv * 2 + mt;
            const unsigned short* xp = xTb + ((size_t)(hh * W_ + w0 + l15)) * C_;
#pragma unroll
            for (int ks = 0; ks < 2; ++ks)
                afr[mt][ks] = *(const bf16x8*)(xp + ks * 32 + l4 * 8);
        }
    }

    // ---- B fragments (cwb: [g][64k][c] bf16, BN-scale folded) ----
    bf16x8 bfr[4][2];
    {
        const unsigned short* cwg = cwb + (size_t)g * 64 * C_;
#pragma unroll
        for (int nt = 0; nt < 4; ++nt) {
            const int k = nt * 16 + l15;
#pragma unroll
            for (int ks = 0; ks < 2; ++ks)
                bfr[nt][ks] = *(const bf16x8*)(cwg + k * C_ + ks * 32 + l4 * 8);
        }
    }

    __syncthreads();

    // ---- MFMA: z[px][k] (batched: 16 independent MFMA pairs, r17 style) ----
    f32x4 acc1[2][4];
#pragma unroll
    for (int mt = 0; mt < 2; ++mt)
#pragma unroll
        for (int nt = 0; nt < 4; ++nt) {
            f32x4 a = {0.f, 0.f, 0.f, 0.f};
            a = __builtin_amdgcn_mfma_f32_16x16x32_bf16(afr[mt][0], bfr[nt][0], a, 0, 0, 0);
            a = __builtin_amdgcn_mfma_f32_16x16x32_bf16(afr[mt][1], bfr[nt][1], a, 0, 0, 0);
            acc1[mt][nt] = a;
        }

    // ---- epilogue: +bias, SiLU -> f16 -> swizzled z (+ 8th-tap pad zero) ----
#pragma unroll
    for (int nt = 0; nt < 4; ++nt) {
        const int k = nt * 16 + l15;
        if (k < KK) {
            const int kh = (k * 9363) >> 16;        // k/7
            const int kw = k - kh * 7;
            const int kbase = kh * ZKHB + kw * 2;
            const float bi = sbias[k];
#pragma unroll
            for (int mt = 0; mt < 2; ++mt) {
                const int px0 = (wv * 2 + mt) * 16 + l4 * 4;
#pragma unroll
                for (int r = 0; r < 4; ++r) {
                    const int px = px0 + r;
                    const int sw = (px << 4) ^ (((px >> 3) & 7) << 4);
                    const float t = acc1[mt][nt][r] + bi;
                    const float v = __fdividef(t, 1.0f + __expf(-t));
                    *(unsigned short*)(z_sh + kbase + sw) = f16b(v);
                }
            }
        } else if (k < 56) {
            const int khp = k - KK;
#pragma unroll
            for (int mt = 0; mt < 2; ++mt) {
                const int px0 = (wv * 2 + mt) * 16 + l4 * 4;
#pragma unroll
                for (int r = 0; r < 4; ++r) {
                    const int px = px0 + r;
                    const int sw = (px << 4) ^ (((px >> 3) & 7) << 4);
                    *(unsigned short*)(z_sh + khp * ZKHB + sw + 14) = 0;
                }
            }
        }
    }

    __syncthreads();

    // ---- involution: f16 dot2, 3-deep row pipeline ----
    float a0 = 0.f, a1 = 0.f, a2 = 0.f, a3 = 0.f;
    float a4 = 0.f, a5 = 0.f, a6 = 0.f, a7 = 0.f;

    const int pxb = y8 * 16 + xh * 8;
    const int mx  = ((2 * y8 + xh) & 7) << 4;
    const char* zbase = z_sh + (pxb << 4);
    const char* zp0 = zbase + ((0 << 4) ^ mx);
    const char* zp1 = zbase + ((1 << 4) ^ mx);
    const char* zp2 = zbase + ((2 << 4) ^ mx);
    const char* zp3 = zbase + ((3 << 4) ^ mx);
    const char* zp4 = zbase + ((4 << 4) ^ mx);
    const char* zp5 = zbase + ((5 << 4) ^ mx);
    const char* zp6 = zbase + ((6 << 4) ^ mx);
    const char* zp7 = zbase + ((7 << 4) ^ mx);

    // 3-deep software pipeline over kh = 0..6 (A/B/C rotate; fully unrolled
    // schedule below keeps every index compile-time; acc + 3x(q,d) ~ 80 VGPR)
    LOADQ(B, 1);
    LOADQ(C, 2);
    PACKD(A); FMAD(A, 0);
    LOADQ(A, 3);
    PACKD(B); FMAD(B, 1);
    LOADQ(B, 4);
    PACKD(C); FMAD(C, 2);
    LOADQ(C, 5);
    PACKD(A); FMAD(A, 3);
    LOADQ(A, 6);
    PACKD(B); FMAD(B, 4);
    PACKD(C); FMAD(C, 5);
    PACKD(A); FMAD(A, 6);

    float* og = out + (size_t)(b * C_ + g * GC_ + c2) * HW_
                    + (h0 + y8) * W_ + w0 + xh * 8;
    {
        f32x4 v;
        v[0] = a0; v[1] = a1; v[2] = a2; v[3] = a3;
        *(f32x4*)(og + 0) = v;
        v[0] = a4; v[1] = a5; v[2] = a6; v[3] = a7;
        *(f32x4*)(og + 4) = v;
    }
}

extern "C" void kernel_launch(void* const* d_in, const int* in_sizes, int n_in,
                              void* d_out, int out_size, void* d_ws, size_t ws_size,
                              hipStream_t stream) {
    const float* x   = (const float*)d_in[0];
    const float* cw  = (const float*)d_in[1];
    const float* bng = (const float*)d_in[2];
    const float* bnb = (const float*)d_in[3];
    const float* bnm = (const float*)d_in[4];
    const float* bnv = (const float*)d_in[5];
    float* out = (float*)d_out;

    unsigned short* xT  = (unsigned short*)d_ws;                 // 8,388,608 B
    unsigned short* cwb = xT + (size_t)B_ * HW_ * C_;            // 32,768 B
    float*          sbp = (float*)(cwb + (size_t)G_ * 64 * C_);  // 784 B

    prep<<<dim3(1025), dim3(256), 0, stream>>>(x, cw, bng, bnb, bnm, bnv,
                                               xT, cwb, sbp);
    invol_mfma15<<<dim3(2048), dim3(256), 0, stream>>>(x, xT, cwb, sbp, out);
}

// Round 23
// 37.822 us; speedup vs baseline: 1.2857x; 1.2374x over previous
//
#include <hip/hip_runtime.h>

#define B_   4
#define C_   64
#define H_   128
#define W_   128
#define KS   7
#define G_   4
#define GC_  16
#define KK   49
#define PAD  3
#define TH   8
#define TW   16
#define HW_  (H_ * W_)
#define ZKHB 2112              // bytes per kh plane: 128px*16B + 64B bank shift

// LDS layout (bytes). z (14784) unions with the x-tile region (dead after
// A-frag reads, which complete before the barrier preceding z writes).
#define XOFF 0                 // x-tile [128px][68 bf16] stride 136B = 17408
#define WOFF 17408             // w-tile [64k][68 bf16]  stride 136B =  8704
#define SCOFF 26112            // folded scale, 49 f32
#define SBOFF 26312            // folded bias,  49 f32
#define LDSZ 26512

typedef float f32x4  __attribute__((ext_vector_type(4)));
typedef short bf16x8 __attribute__((ext_vector_type(8)));
typedef short bf16x4 __attribute__((ext_vector_type(4)));
typedef unsigned int u32x4 __attribute__((ext_vector_type(4)));
typedef __fp16 h16x2 __attribute__((ext_vector_type(2)));

__device__ __forceinline__ unsigned f2bf(float f) {
    unsigned u = __float_as_uint(f);
    unsigned r = u + 0x7FFFu + ((u >> 16) & 1u);
    return r >> 16;
}
__device__ __forceinline__ unsigned pk2(float a, float b) {
    union { h16x2 h; unsigned u; } x;
    x.h = __builtin_amdgcn_cvt_pkrtz(a, b);
    return x.u;
}
__device__ __forceinline__ h16x2 ash2(unsigned u) {
    union { unsigned u; h16x2 h; } x; x.u = u; return x.h;
}
__device__ __forceinline__ unsigned short f16b(float f) {
    union { __fp16 h; unsigned short s; } x; x.h = (__fp16)f; return x.s;
}
#if __has_builtin(__builtin_amdgcn_fdot2)
#define DOT2(a, b, c) __builtin_amdgcn_fdot2((a), (b), (c), false)
#else
#define DOT2(a, b, c) ((c) + (float)(a)[0] * (float)(b)[0] + (float)(a)[1] * (float)(b)[1])
#endif
#define AB(a, b) __builtin_amdgcn_alignbit((a), (b), 16)

// ---- involution phase macros: pure named-SSA (r16 lesson) ----
#define LOADQ(S, KH_) do {                                                     \
    const int gh_  = h0 + y8 + (KH_) - PAD;                                    \
    const int ghc_ = gh_ < 0 ? 0 : (gh_ > H_ - 1 ? H_ - 1 : gh_);              \
    const float* rp_ = xc + (size_t)ghc_ * W_;                                 \
    if (ledge) {                                                               \
        const f32x4* vp_ = (const f32x4*)rp_;                                  \
        q##S##0 = vp_[0]; q##S##1 = vp_[1]; q##S##2 = vp_[2];                  \
    } else if (redge) {                                                        \
        const f32x4* vp_ = (const f32x4*)(rp_ + 116);                          \
        q##S##0 = vp_[0]; q##S##1 = vp_[1]; q##S##2 = vp_[2];                  \
    } else {                                                                   \
        const f32x4* vp_ = (const f32x4*)(rp_ + w0 + xh * 8 - 4);              \
        q##S##0 = vp_[0]; q##S##1 = vp_[1]; q##S##2 = vp_[2]; q##S##3 = vp_[3];\
    }                                                                          \
} while (0)

#define PACKD(S) do {                                                          \
    if (ledge) {                                                               \
        d##S##0 = 0u;                                                          \
        d##S##1 = pk2(0.f, q##S##0[0]);                                        \
        d##S##2 = pk2(q##S##0[1], q##S##0[2]);                                 \
        d##S##3 = pk2(q##S##0[3], q##S##1[0]);                                 \
        d##S##4 = pk2(q##S##1[1], q##S##1[2]);                                 \
        d##S##5 = pk2(q##S##1[3], q##S##2[0]);                                 \
        d##S##6 = pk2(q##S##2[1], q##S##2[2]);                                 \
    } else if (redge) {                                                        \
        d##S##0 = pk2(q##S##0[1], q##S##0[2]);                                 \
        d##S##1 = pk2(q##S##0[3], q##S##1[0]);                                 \
        d##S##2 = pk2(q##S##1[1], q##S##1[2]);                                 \
        d##S##3 = pk2(q##S##1[3], q##S##2[0]);                                 \
        d##S##4 = pk2(q##S##2[1], q##S##2[2]);                                 \
        d##S##5 = pk2(q##S##2[3], 0.f);                                        \
        d##S##6 = 0u;                                                          \
    } else {                                                                   \
        d##S##0 = pk2(q##S##0[1], q##S##0[2]);                                 \
        d##S##1 = pk2(q##S##0[3], q##S##1[0]);                                 \
        d##S##2 = pk2(q##S##1[1], q##S##1[2]);                                 \
        d##S##3 = pk2(q##S##1[3], q##S##2[0]);                                 \
        d##S##4 = pk2(q##S##2[1], q##S##2[2]);                                 \
        d##S##5 = pk2(q##S##2[3], q##S##3[0]);                                 \
        d##S##6 = pk2(q##S##3[1], q##S##3[2]);                                 \
    }                                                                          \
} while (0)

#define FMAD(S, KH_) do {                                                      \
    const int gh_ = h0 + y8 + (KH_) - PAD;                                     \
    if (gh_ >= 0 && gh_ < H_) {                                                \
        const int zo_ = (KH_) * ZKHB;                                          \
        const unsigned r0_ = AB(d##S##1, d##S##0);                             \
        const unsigned r1_ = AB(d##S##2, d##S##1);                             \
        const unsigned r2_ = AB(d##S##3, d##S##2);                             \
        const unsigned r3_ = AB(d##S##4, d##S##3);                             \
        const unsigned r4_ = AB(d##S##5, d##S##4);                             \
        const unsigned r5_ = AB(d##S##6, d##S##5);                             \
        const unsigned r6_ = AB(d##S##6, d##S##6);                             \
        u32x4 q_;                                                              \
        q_ = *(const u32x4*)(zp0 + zo_);                                       \
        a0 = DOT2(ash2(q_[0]), ash2(d##S##0), a0);                             \
        a0 = DOT2(ash2(q_[1]), ash2(d##S##1), a0);                             \
        a0 = DOT2(ash2(q_[2]), ash2(d##S##2), a0);                             \
        a0 = DOT2(ash2(q_[3]), ash2(d##S##3), a0);                             \
        q_ = *(const u32x4*)(zp1 + zo_);                                       \
        a1 = DOT2(ash2(q_[0]), ash2(r0_), a1);                                 \
        a1 = DOT2(ash2(q_[1]), ash2(r1_), a1);                                 \
        a1 = DOT2(ash2(q_[2]), ash2(r2_), a1);                                 \
        a1 = DOT2(ash2(q_[3]), ash2(r3_), a1);                                 \
        q_ = *(const u32x4*)(zp2 + zo_);                                       \
        a2 = DOT2(ash2(q_[0]), ash2(d##S##1), a2);                             \
        a2 = DOT2(ash2(q_[1]), ash2(d##S##2), a2);                             \
        a2 = DOT2(ash2(q_[2]), ash2(d##S##3), a2);                             \
        a2 = DOT2(ash2(q_[3]), ash2(d##S##4), a2);                             \
        q_ = *(const u32x4*)(zp3 + zo_);                                       \
        a3 = DOT2(ash2(q_[0]), ash2(r1_), a3);                                 \
        a3 = DOT2(ash2(q_[1]), ash2(r2_), a3);                                 \
        a3 = DOT2(ash2(q_[2]), ash2(r3_), a3);                                 \
        a3 = DOT2(ash2(q_[3]), ash2(r4_), a3);                                 \
        q_ = *(const u32x4*)(zp4 + zo_);                                       \
        a4 = DOT2(ash2(q_[0]), ash2(d##S##2), a4);                             \
        a4 = DOT2(ash2(q_[1]), ash2(d##S##3), a4);                             \
        a4 = DOT2(ash2(q_[2]), ash2(d##S##4), a4);                             \
        a4 = DOT2(ash2(q_[3]), ash2(d##S##5), a4);                             \
        q_ = *(const u32x4*)(zp5 + zo_);                                       \
        a5 = DOT2(ash2(q_[0]), ash2(r2_), a5);                                 \
        a5 = DOT2(ash2(q_[1]), ash2(r3_), a5);                                 \
        a5 = DOT2(ash2(q_[2]), ash2(r4_), a5);                                 \
        a5 = DOT2(ash2(q_[3]), ash2(r5_), a5);                                 \
        q_ = *(const u32x4*)(zp6 + zo_);                                       \
        a6 = DOT2(ash2(q_[0]), ash2(d##S##3), a6);                             \
        a6 = DOT2(ash2(q_[1]), ash2(d##S##4), a6);                             \
        a6 = DOT2(ash2(q_[2]), ash2(d##S##5), a6);                             \
        a6 = DOT2(ash2(q_[3]), ash2(d##S##6), a6);                             \
        q_ = *(const u32x4*)(zp7 + zo_);                                       \
        a7 = DOT2(ash2(q_[0]), ash2(r3_), a7);                                 \
        a7 = DOT2(ash2(q_[1]), ash2(r4_), a7);                                 \
        a7 = DOT2(ash2(q_[2]), ash2(r5_), a7);                                 \
        a7 = DOT2(ash2(q_[3]), ash2(r6_), a7);                                 \
    }                                                                          \
} while (0)

// ======== single fused kernel: in-block staging + MFMA conv + dot2 invol ====
__global__ __launch_bounds__(256, 4) void invol_fused16(
    const float* __restrict__ x,
    const float* __restrict__ cw,
    const float* __restrict__ bng,
    const float* __restrict__ bnb,
    const float* __restrict__ bnm,
    const float* __restrict__ bnv,
    float* __restrict__ out)
{
    __shared__ __align__(16) char lds[LDSZ];

    const int tid  = threadIdx.x;
    const int lane = tid & 63;
    const int wv   = tid >> 6;
    const int l15  = lane & 15;
    const int l4   = lane >> 4;

    // XCD-locality swizzle (r13: FETCH 37->27 MB)
    const int bid = blockIdx.x;
    const int xcd = bid & 7;
    const int s   = bid >> 3;
    const int b   = xcd >> 1;
    const int g   = (xcd & 1) * 2 + (s >> 7);
    const int by  = (s >> 3) & 15;
    const int bx  = s & 7;
    const int w0  = bx * TW;
    const int h0  = by * TH;

    // involution thread mapping (r17 proven variant)
    const int c2 = tid >> 4;
    const int y8 = (tid >> 1) & 7;
    const int xh = tid & 1;
    const bool ledge = (bx == 0) & (xh == 0);
    const bool redge = (bx == W_ / TW - 1) & (xh == 1);
    const float* xc = x + (size_t)(b * C_ + g * GC_ + c2) * HW_;

    f32x4 qA0 = {0,0,0,0}, qA1 = {0,0,0,0}, qA2 = {0,0,0,0}, qA3 = {0,0,0,0};
    f32x4 qB0 = {0,0,0,0}, qB1 = {0,0,0,0}, qB2 = {0,0,0,0}, qB3 = {0,0,0,0};
    unsigned dA0, dA1, dA2, dA3, dA4, dA5, dA6;
    unsigned dB0, dB1, dB2, dB3, dB4, dB5, dB6;

    LOADQ(A, 0);   // first involution row in flight under the whole conv phase

    // ---- stage x-tile: [128px][c] bf16, stride 68 bf16 (136 B) ----
    // per-thread: p fixed, c = 2*it + (tid>>7)  -> loop-invariant addressing
    {
        const float* xb = x + (size_t)b * C_ * HW_;
        const int p  = tid & 127;
        const int cb = tid >> 7;
        const float* src = xb + (size_t)cb * HW_ + (h0 + (p >> 4)) * W_ + w0 + (p & 15);
        char* dst = lds + XOFF + p * 136 + cb * 2;
#pragma unroll
        for (int it = 0; it < 32; ++it) {
            *(unsigned short*)(dst + it * 4) =
                (unsigned short)f2bf(src[(size_t)(2 * it) * HW_]);
        }
    }

    // ---- folded BN scale/bias -> LDS ----
    if (tid < KK) {
        const int o = g * KK + tid;
        const float scv = bng[o] * rsqrtf(bnv[o] + 1e-5f);
        *(float*)(lds + SCOFF + tid * 4) = scv;
        *(float*)(lds + SBOFF + tid * 4) = bnb[o] - bnm[o] * scv;
    }

    __syncthreads();   // x-tile + sc/sb staged

    // ---- stage w-tile: [64k][c] bf16 (scale-folded, rows 49..63 zero) ----
    {
        const float* cwg = cw + (size_t)g * KK * C_;
        const int c  = tid & 63;
        const int kb = tid >> 6;
#pragma unroll
        for (int it = 0; it < 16; ++it) {
            const int k = it * 4 + kb;
            float v = 0.f;
            if (k < KK)
                v = cwg[k * C_ + c] * *(const float*)(lds + SCOFF + k * 4);
            *(unsigned short*)(lds + WOFF + k * 136 + c * 2) = (unsigned short)f2bf(v);
        }
    }

    // ---- A fragments from x-tile (2x ds_read_b64 each) ----
    bf16x8 afr[2][2];
#pragma unroll
    for (int mt = 0; mt < 2; ++mt) {
        const int px = (wv * 2 + mt) * 16 + l15;
        const char* base_ = lds + XOFF + px * 136;
#pragma unroll
        for (int ks = 0; ks < 2; ++ks) {
            const char* pA = base_ + ks * 64 + l4 * 16;
            const bf16x4 lo = *(const bf16x4*)(pA);
            const bf16x4 hi = *(const bf16x4*)(pA + 8);
            bf16x8 f;
            f[0] = lo[0]; f[1] = lo[1]; f[2] = lo[2]; f[3] = lo[3];
            f[4] = hi[0]; f[5] = hi[1]; f[6] = hi[2]; f[7] = hi[3];
            afr[mt][ks] = f;
        }
    }

    __syncthreads();   // w-tile staged; all x-tile reads done (z may overwrite)

    // ---- B fragments from w-tile ----
    bf16x8 bfr[4][2];
#pragma unroll
    for (int nt = 0; nt < 4; ++nt) {
        const int k = nt * 16 + l15;
        const char* base_ = lds + WOFF + k * 136;
#pragma unroll
        for (int ks = 0; ks < 2; ++ks) {
            const char* pB = base_ + ks * 64 + l4 * 16;
            const bf16x4 lo = *(const bf16x4*)(pB);
            const bf16x4 hi = *(const bf16x4*)(pB + 8);
            bf16x8 f;
            f[0] = lo[0]; f[1] = lo[1]; f[2] = lo[2]; f[3] = lo[3];
            f[4] = hi[0]; f[5] = hi[1]; f[6] = hi[2]; f[7] = hi[3];
            bfr[nt][ks] = f;
        }
    }

    // ---- MFMA: z[px][k] (16 independent MFMA pairs, r17 style) ----
    f32x4 acc1[2][4];
#pragma unroll
    for (int mt = 0; mt < 2; ++mt)
#pragma unroll
        for (int nt = 0; nt < 4; ++nt) {
            f32x4 a = {0.f, 0.f, 0.f, 0.f};
            a = __builtin_amdgcn_mfma_f32_16x16x32_bf16(afr[mt][0], bfr[nt][0], a, 0, 0, 0);
            a = __builtin_amdgcn_mfma_f32_16x16x32_bf16(afr[mt][1], bfr[nt][1], a, 0, 0, 0);
            acc1[mt][nt] = a;
        }

    // ---- epilogue: +bias, SiLU -> f16 -> swizzled z (+ 8th-tap pad zero) ----
    // z region unions with the (now dead) x-tile.
#pragma unroll
    for (int nt = 0; nt < 4; ++nt) {
        const int k = nt * 16 + l15;
        if (k < KK) {
            const int kh = (k * 9363) >> 16;        // k/7
            const int kw = k - kh * 7;
            const int kbase = kh * ZKHB + kw * 2;
            const float bi = *(const float*)(lds + SBOFF + k * 4);
#pragma unroll
            for (int mt = 0; mt < 2; ++mt) {
                const int px0 = (wv * 2 + mt) * 16 + l4 * 4;
#pragma unroll
                for (int r = 0; r < 4; ++r) {
                    const int px = px0 + r;
                    const int sw = (px << 4) ^ (((px >> 3) & 7) << 4);
                    const float t = acc1[mt][nt][r] + bi;
                    const float v = __fdividef(t, 1.0f + __expf(-t));
                    *(unsigned short*)(lds + kbase + sw) = f16b(v);
                }
            }
        } else if (k < 56) {
            const int khp = k - KK;
#pragma unroll
            for (int mt = 0; mt < 2; ++mt) {
                const int px0 = (wv * 2 + mt) * 16 + l4 * 4;
#pragma unroll
                for (int r = 0; r < 4; ++r) {
                    const int px = px0 + r;
                    const int sw = (px << 4) ^ (((px >> 3) & 7) << 4);
                    *(unsigned short*)(lds + khp * ZKHB + sw + 14) = 0;
                }
            }
        }
    }

    __syncthreads();   // z visible

    // ---- involution: f16 dot2, 2-deep row pipeline (r17 exact) ----
    float a0 = 0.f, a1 = 0.f, a2 = 0.f, a3 = 0.f;
    float a4 = 0.f, a5 = 0.f, a6 = 0.f, a7 = 0.f;

    const int pxb = y8 * 16 + xh * 8;
    const int mx  = ((2 * y8 + xh) & 7) << 4;
    const char* zbase = lds + (pxb << 4);
    const char* zp0 = zbase + ((0 << 4) ^ mx);
    const char* zp1 = zbase + ((1 << 4) ^ mx);
    const char* zp2 = zbase + ((2 << 4) ^ mx);
    const char* zp3 = zbase + ((3 << 4) ^ mx);
    const char* zp4 = zbase + ((4 << 4) ^ mx);
    const char* zp5 = zbase + ((5 << 4) ^ mx);
    const char* zp6 = zbase + ((6 << 4) ^ mx);
    const char* zp7 = zbase + ((7 << 4) ^ mx);

#pragma unroll 1
    for (int kh2 = 0; kh2 < 3; ++kh2) {             // kh rolled (r4 spill lesson)
        LOADQ(B, 2 * kh2 + 1);
        PACKD(A); FMAD(A, 2 * kh2);
        LOADQ(A, 2 * kh2 + 2);
        PACKD(B); FMAD(B, 2 * kh2 + 1);
    }
    PACKD(A); FMAD(A, 6);

    float* og = out + (size_t)(b * C_ + g * GC_ + c2) * HW_
                    + (h0 + y8) * W_ + w0 + xh * 8;
    {
        f32x4 v;
        v[0] = a0; v[1] = a1; v[2] = a2; v[3] = a3;
        *(f32x4*)(og + 0) = v;
        v[0] = a4; v[1] = a5; v[2] = a6; v[3] = a7;
        *(f32x4*)(og + 4) = v;
    }
}

extern "C" void kernel_launch(void* const* d_in, const int* in_sizes, int n_in,
                              void* d_out, int out_size, void* d_ws, size_t ws_size,
                              hipStream_t stream) {
    const float* x   = (const float*)d_in[0];
    const float* cw  = (const float*)d_in[1];
    const float* bng = (const float*)d_in[2];
    const float* bnb = (const float*)d_in[3];
    const float* bnm = (const float*)d_in[4];
    const float* bnv = (const float*)d_in[5];
    float* out = (float*)d_out;

    invol_fused16<<<dim3(2048), dim3(256), 0, stream>>>(x, cw, bng, bnb, bnm,
                                                        bnv, out);
}

// Round 24
// 33.507 us; speedup vs baseline: 1.4513x; 1.1288x over previous
//
#include <hip/hip_runtime.h>

#define B_   4
#define C_   64
#define H_   128
#define W_   128
#define KS   7
#define G_   4
#define GC_  16
#define KK   49
#define PAD  3
#define TH   8
#define TW   16
#define HW_  (H_ * W_)
#define ZKHB 2112              // bytes per kh plane: 128px*16B + 64B bank shift

// LDS layout (bytes): z [0, 14784) | w-tile [14784, 23488) | sc/sb
#define WOFF  14784            // w-tile [64k][68 bf16] stride 136B = 8704
#define SCOFF 23488            // folded scale, 49 f32
#define SBOFF 23688            // folded bias,  49 f32
#define LDSZ  23888

typedef float f32x4  __attribute__((ext_vector_type(4)));
typedef short bf16x8 __attribute__((ext_vector_type(8)));
typedef short bf16x4 __attribute__((ext_vector_type(4)));
typedef unsigned int u32x4 __attribute__((ext_vector_type(4)));
typedef __fp16 h16x2 __attribute__((ext_vector_type(2)));

__device__ __forceinline__ unsigned f2bf(float f) {
    unsigned u = __float_as_uint(f);
    unsigned r = u + 0x7FFFu + ((u >> 16) & 1u);
    return r >> 16;
}
__device__ __forceinline__ unsigned pk2(float a, float b) {
    union { h16x2 h; unsigned u; } x;
    x.h = __builtin_amdgcn_cvt_pkrtz(a, b);
    return x.u;
}
__device__ __forceinline__ h16x2 ash2(unsigned u) {
    union { unsigned u; h16x2 h; } x; x.u = u; return x.h;
}
__device__ __forceinline__ unsigned short f16b(float f) {
    union { __fp16 h; unsigned short s; } x; x.h = (__fp16)f; return x.s;
}
#if __has_builtin(__builtin_amdgcn_fdot2)
#define DOT2(a, b, c) __builtin_amdgcn_fdot2((a), (b), (c), false)
#else
#define DOT2(a, b, c) ((c) + (float)(a)[0] * (float)(b)[0] + (float)(a)[1] * (float)(b)[1])
#endif
#define AB(a, b) __builtin_amdgcn_alignbit((a), (b), 16)

// ---- involution phase macros: pure named-SSA (r16 lesson) ----
#define LOADQ(S, KH_) do {                                                     \
    const int gh_  = h0 + y8 + (KH_) - PAD;                                    \
    const int ghc_ = gh_ < 0 ? 0 : (gh_ > H_ - 1 ? H_ - 1 : gh_);              \
    const float* rp_ = xc + (size_t)ghc_ * W_;                                 \
    if (ledge) {                                                               \
        const f32x4* vp_ = (const f32x4*)rp_;                                  \
        q##S##0 = vp_[0]; q##S##1 = vp_[1]; q##S##2 = vp_[2];                  \
    } else if (redge) {                                                        \
        const f32x4* vp_ = (const f32x4*)(rp_ + 116);                          \
        q##S##0 = vp_[0]; q##S##1 = vp_[1]; q##S##2 = vp_[2];                  \
    } else {                                                                   \
        const f32x4* vp_ = (const f32x4*)(rp_ + w0 + xh * 8 - 4);              \
        q##S##0 = vp_[0]; q##S##1 = vp_[1]; q##S##2 = vp_[2]; q##S##3 = vp_[3];\
    }                                                                          \
} while (0)

#define PACKD(S) do {                                                          \
    if (ledge) {                                                               \
        d##S##0 = 0u;                                                          \
        d##S##1 = pk2(0.f, q##S##0[0]);                                        \
        d##S##2 = pk2(q##S##0[1], q##S##0[2]);                                 \
        d##S##3 = pk2(q##S##0[3], q##S##1[0]);                                 \
        d##S##4 = pk2(q##S##1[1], q##S##1[2]);                                 \
        d##S##5 = pk2(q##S##1[3], q##S##2[0]);                                 \
        d##S##6 = pk2(q##S##2[1], q##S##2[2]);                                 \
    } else if (redge) {                                                        \
        d##S##0 = pk2(q##S##0[1], q##S##0[2]);                                 \
        d##S##1 = pk2(q##S##0[3], q##S##1[0]);                                 \
        d##S##2 = pk2(q##S##1[1], q##S##1[2]);                                 \
        d##S##3 = pk2(q##S##1[3], q##S##2[0]);                                 \
        d##S##4 = pk2(q##S##2[1], q##S##2[2]);                                 \
        d##S##5 = pk2(q##S##2[3], 0.f);                                        \
        d##S##6 = 0u;                                                          \
    } else {                                                                   \
        d##S##0 = pk2(q##S##0[1], q##S##0[2]);                                 \
        d##S##1 = pk2(q##S##0[3], q##S##1[0]);                                 \
        d##S##2 = pk2(q##S##1[1], q##S##1[2]);                                 \
        d##S##3 = pk2(q##S##1[3], q##S##2[0]);                                 \
        d##S##4 = pk2(q##S##2[1], q##S##2[2]);                                 \
        d##S##5 = pk2(q##S##2[3], q##S##3[0]);                                 \
        d##S##6 = pk2(q##S##3[1], q##S##3[2]);                                 \
    }                                                                          \
} while (0)

#define FMAD(S, KH_) do {                                                      \
    const int gh_ = h0 + y8 + (KH_) - PAD;                                     \
    if (gh_ >= 0 && gh_ < H_) {                                                \
        const int zo_ = (KH_) * ZKHB;                                          \
        const unsigned r0_ = AB(d##S##1, d##S##0);                             \
        const unsigned r1_ = AB(d##S##2, d##S##1);                             \
        const unsigned r2_ = AB(d##S##3, d##S##2);                             \
        const unsigned r3_ = AB(d##S##4, d##S##3);                             \
        const unsigned r4_ = AB(d##S##5, d##S##4);                             \
        const unsigned r5_ = AB(d##S##6, d##S##5);                             \
        const unsigned r6_ = AB(d##S##6, d##S##6);                             \
        u32x4 q_;                                                              \
        q_ = *(const u32x4*)(zp0 + zo_);                                       \
        a0 = DOT2(ash2(q_[0]), ash2(d##S##0), a0);                             \
        a0 = DOT2(ash2(q_[1]), ash2(d##S##1), a0);                             \
        a0 = DOT2(ash2(q_[2]), ash2(d##S##2), a0);                             \
        a0 = DOT2(ash2(q_[3]), ash2(d##S##3), a0);                             \
        q_ = *(const u32x4*)(zp1 + zo_);                                       \
        a1 = DOT2(ash2(q_[0]), ash2(r0_), a1);                                 \
        a1 = DOT2(ash2(q_[1]), ash2(r1_), a1);                                 \
        a1 = DOT2(ash2(q_[2]), ash2(r2_), a1);                                 \
        a1 = DOT2(ash2(q_[3]), ash2(r3_), a1);                                 \
        q_ = *(const u32x4*)(zp2 + zo_);                                       \
        a2 = DOT2(ash2(q_[0]), ash2(d##S##1), a2);                             \
        a2 = DOT2(ash2(q_[1]), ash2(d##S##2), a2);                             \
        a2 = DOT2(ash2(q_[2]), ash2(d##S##3), a2);                             \
        a2 = DOT2(ash2(q_[3]), ash2(d##S##4), a2);                             \
        q_ = *(const u32x4*)(zp3 + zo_);                                       \
        a3 = DOT2(ash2(q_[0]), ash2(r1_), a3);                                 \
        a3 = DOT2(ash2(q_[1]), ash2(r2_), a3);                                 \
        a3 = DOT2(ash2(q_[2]), ash2(r3_), a3);                                 \
        a3 = DOT2(ash2(q_[3]), ash2(r4_), a3);                                 \
        q_ = *(const u32x4*)(zp4 + zo_);                                       \
        a4 = DOT2(ash2(q_[0]), ash2(d##S##2), a4);                             \
        a4 = DOT2(ash2(q_[1]), ash2(d##S##3), a4);                             \
        a4 = DOT2(ash2(q_[2]), ash2(d##S##4), a4);                             \
        a4 = DOT2(ash2(q_[3]), ash2(d##S##5), a4);                             \
        q_ = *(const u32x4*)(zp5 + zo_);                                       \
        a5 = DOT2(ash2(q_[0]), ash2(r2_), a5);                                 \
        a5 = DOT2(ash2(q_[1]), ash2(r3_), a5);                                 \
        a5 = DOT2(ash2(q_[2]), ash2(r4_), a5);                                 \
        a5 = DOT2(ash2(q_[3]), ash2(r5_), a5);                                 \
        q_ = *(const u32x4*)(zp6 + zo_);                                       \
        a6 = DOT2(ash2(q_[0]), ash2(d##S##3), a6);                             \
        a6 = DOT2(ash2(q_[1]), ash2(d##S##4), a6);                             \
        a6 = DOT2(ash2(q_[2]), ash2(d##S##5), a6);                             \
        a6 = DOT2(ash2(q_[3]), ash2(d##S##6), a6);                             \
        q_ = *(const u32x4*)(zp7 + zo_);                                       \
        a7 = DOT2(ash2(q_[0]), ash2(r3_), a7);                                 \
        a7 = DOT2(ash2(q_[1]), ash2(r4_), a7);                                 \
        a7 = DOT2(ash2(q_[2]), ash2(r5_), a7);                                 \
        a7 = DOT2(ash2(q_[3]), ash2(r6_), a7);                                 \
    }                                                                          \
} while (0)

// ======== fused kernel v2: direct A-gather, 1 barrier, wave-sync z ========
// vs r23 (37.8us): x-tile LDS round-trip deleted (A-frags gathered straight
// from global -- same loads, no ds_write/ds_read/barrier); z-visibility
// barrier deleted via r18 wave-synchronous consumer map (wave consumes the z
// rows it produced); z and w-tile in disjoint LDS so the one remaining
// barrier is the w-stage fence.
__global__ __launch_bounds__(256, 4) void invol_fused17(
    const float* __restrict__ x,
    const float* __restrict__ cw,
    const float* __restrict__ bng,
    const float* __restrict__ bnb,
    const float* __restrict__ bnm,
    const float* __restrict__ bnv,
    float* __restrict__ out)
{
    __shared__ __align__(16) char lds[LDSZ];

    const int tid  = threadIdx.x;
    const int lane = tid & 63;
    const int wv   = tid >> 6;
    const int l15  = lane & 15;
    const int l4   = lane >> 4;

    // XCD-locality swizzle (r13: FETCH 37->27 MB)
    const int bid = blockIdx.x;
    const int xcd = bid & 7;
    const int s   = bid >> 3;
    const int b   = xcd >> 1;
    const int g   = (xcd & 1) * 2 + (s >> 7);
    const int by  = (s >> 3) & 15;
    const int bx  = s & 7;
    const int w0  = bx * TW;
    const int h0  = by * TH;

    // wave-synchronous consumer map (r18: wave consumes its own z rows)
    const int y8 = tid >> 5;           // wave = y8>>1 (= wv)
    const int c2 = (tid >> 1) & 15;
    const int xh = tid & 1;
    const bool ledge = (bx == 0) & (xh == 0);
    const bool redge = (bx == W_ / TW - 1) & (xh == 1);
    const float* xc = x + (size_t)(b * C_ + g * GC_ + c2) * HW_;

    f32x4 qA0 = {0,0,0,0}, qA1 = {0,0,0,0}, qA2 = {0,0,0,0}, qA3 = {0,0,0,0};
    f32x4 qB0 = {0,0,0,0}, qB1 = {0,0,0,0}, qB2 = {0,0,0,0}, qB3 = {0,0,0,0};
    unsigned dA0, dA1, dA2, dA3, dA4, dA5, dA6;
    unsigned dB0, dB1, dB2, dB3, dB4, dB5, dB6;

    LOADQ(A, 0);   // first involution row in flight under the whole conv phase

    // ---- stage w-tile + folded sc/sb (one barrier below covers all) ----
    if (tid < KK) {
        const int o = g * KK + tid;
        const float scv = bng[o] * rsqrtf(bnv[o] + 1e-5f);
        *(float*)(lds + SCOFF + tid * 4) = scv;
        *(float*)(lds + SBOFF + tid * 4) = bnb[o] - bnm[o] * scv;
    }
    __builtin_amdgcn_s_barrier();   // scale visible for w-fold below
    {
        const float* cwg = cw + (size_t)g * KK * C_;
        const int c  = tid & 63;
        const int kb = tid >> 6;
#pragma unroll
        for (int it = 0; it < 16; ++it) {
            const int k = it * 4 + kb;
            float v = 0.f;
            if (k < KK)
                v = cwg[k * C_ + c] * *(const float*)(lds + SCOFF + k * 4);
            *(unsigned short*)(lds + WOFF + k * 136 + c * 2) = (unsigned short)f2bf(v);
        }
    }

    // ---- A fragments: direct gather from global x (r13-proven pattern) ----
    bf16x8 afr[2][2];
    {
        const float* xb = x + (size_t)b * C_ * HW_;
#pragma unroll
        for (int mt = 0; mt < 2; ++mt) {
            const int hh = h0 + wv * 2 + mt;
            const float* xp = xb + hh * W_ + (w0 + l15);
#pragma unroll
            for (int ks = 0; ks < 2; ++ks) {
                const int c0 = ks * 32 + l4 * 8;
                bf16x8 a;
#pragma unroll
                for (int j = 0; j < 8; ++j)
                    a[j] = (short)f2bf(xp[(size_t)(c0 + j) * HW_]);
                afr[mt][ks] = a;
            }
        }
    }

    __syncthreads();   // w-tile staged

    // ---- B fragments from w-tile ----
    bf16x8 bfr[4][2];
#pragma unroll
    for (int nt = 0; nt < 4; ++nt) {
        const int k = nt * 16 + l15;
        const char* base_ = lds + WOFF + k * 136;
#pragma unroll
        for (int ks = 0; ks < 2; ++ks) {
            const char* pB = base_ + ks * 64 + l4 * 16;
            const bf16x4 lo = *(const bf16x4*)(pB);
            const bf16x4 hi = *(const bf16x4*)(pB + 8);
            bf16x8 f;
            f[0] = lo[0]; f[1] = lo[1]; f[2] = lo[2]; f[3] = lo[3];
            f[4] = hi[0]; f[5] = hi[1]; f[6] = hi[2]; f[7] = hi[3];
            bfr[nt][ks] = f;
        }
    }

    // ---- MFMA: z rows {2wv, 2wv+1} ----
    f32x4 acc1[2][4];
#pragma unroll
    for (int mt = 0; mt < 2; ++mt)
#pragma unroll
        for (int nt = 0; nt < 4; ++nt) {
            f32x4 a = {0.f, 0.f, 0.f, 0.f};
            a = __builtin_amdgcn_mfma_f32_16x16x32_bf16(afr[mt][0], bfr[nt][0], a, 0, 0, 0);
            a = __builtin_amdgcn_mfma_f32_16x16x32_bf16(afr[mt][1], bfr[nt][1], a, 0, 0, 0);
            acc1[mt][nt] = a;
        }

    // ---- epilogue: +bias, SiLU -> f16 -> swizzled z (wave's own rows) ----
#pragma unroll
    for (int nt = 0; nt < 4; ++nt) {
        const int k = nt * 16 + l15;
        if (k < KK) {
            const int kh = (k * 9363) >> 16;        // k/7
            const int kw = k - kh * 7;
            const int kbase = kh * ZKHB + kw * 2;
            const float bi = *(const float*)(lds + SBOFF + k * 4);
#pragma unroll
            for (int mt = 0; mt < 2; ++mt) {
                const int px0 = (wv * 2 + mt) * 16 + l4 * 4;
#pragma unroll
                for (int r = 0; r < 4; ++r) {
                    const int px = px0 + r;
                    const int sw = (px << 4) ^ (((px >> 3) & 7) << 4);
                    const float t = acc1[mt][nt][r] + bi;
                    const float v = __fdividef(t, 1.0f + __expf(-t));
                    *(unsigned short*)(lds + kbase + sw) = f16b(v);
                }
            }
        } else if (k < 56) {                        // zero the 8th-tap pad
            const int khp = k - KK;
#pragma unroll
            for (int mt = 0; mt < 2; ++mt) {
                const int px0 = (wv * 2 + mt) * 16 + l4 * 4;
#pragma unroll
                for (int r = 0; r < 4; ++r) {
                    const int px = px0 + r;
                    const int sw = (px << 4) ^ (((px >> 3) & 7) << 4);
                    *(unsigned short*)(lds + khp * ZKHB + sw + 14) = 0;
                }
            }
        }
    }

    // NO barrier: consumer map keeps each wave on the z rows it just wrote
    // (wave-internal LDS ops are in-order, r18-proven).

    // ---- involution: f16 dot2, 2-deep row pipeline (r17 exact) ----
    float a0 = 0.f, a1 = 0.f, a2 = 0.f, a3 = 0.f;
    float a4 = 0.f, a5 = 0.f, a6 = 0.f, a7 = 0.f;

    const int pxb = y8 * 16 + xh * 8;
    const int mx  = ((2 * y8 + xh) & 7) << 4;
    const char* zbase = lds + (pxb << 4);
    const char* zp0 = zbase + ((0 << 4) ^ mx);
    const char* zp1 = zbase + ((1 << 4) ^ mx);
    const char* zp2 = zbase + ((2 << 4) ^ mx);
    const char* zp3 = zbase + ((3 << 4) ^ mx);
    const char* zp4 = zbase + ((4 << 4) ^ mx);
    const char* zp5 = zbase + ((5 << 4) ^ mx);
    const char* zp6 = zbase + ((6 << 4) ^ mx);
    const char* zp7 = zbase + ((7 << 4) ^ mx);

#pragma unroll 1
    for (int kh2 = 0; kh2 < 3; ++kh2) {             // kh rolled (r4 spill lesson)
        LOADQ(B, 2 * kh2 + 1);
        PACKD(A); FMAD(A, 2 * kh2);
        LOADQ(A, 2 * kh2 + 2);
        PACKD(B); FMAD(B, 2 * kh2 + 1);
    }
    PACKD(A); FMAD(A, 6);

    float* og = out + (size_t)(b * C_ + g * GC_ + c2) * HW_
                    + (h0 + y8) * W_ + w0 + xh * 8;
    {
        f32x4 v;
        v[0] = a0; v[1] = a1; v[2] = a2; v[3] = a3;
        *(f32x4*)(og + 0) = v;
        v[0] = a4; v[1] = a5; v[2] = a6; v[3] = a7;
        *(f32x4*)(og + 4) = v;
    }
}

extern "C" void kernel_launch(void* const* d_in, const int* in_sizes, int n_in,
                              void* d_out, int out_size, void* d_ws, size_t ws_size,
                              hipStream_t stream) {
    const float* x   = (const float*)d_in[0];
    const float* cw  = (const float*)d_in[1];
    const float* bng = (const float*)d_in[2];
    const float* bnb = (const float*)d_in[3];
    const float* bnm = (const float*)d_in[4];
    const float* bnv = (const float*)d_in[5];
    float* out = (float*)d_out;

    invol_fused17<<<dim3(2048), dim3(256), 0, stream>>>(x, cw, bng, bnb, bnm,
                                                        bnv, out);
}